// Round 18
// baseline (58.939 us; speedup 1.0000x reference)
//
#include <hip/hip_runtime.h>

// TopKGate via split-precision f16 MFMA (no fp32 MFMA on CDNA4):
//   x = xh + xl/4096, w = wh + wl/4096 (f16 planes, lo pre-scaled x4096)
//   logits = xh*wh + (xh*wl' + xl'*wh)/4096
// R18 = R17 + (a) NBUF=4 with stage issued BEFORE compute -> 3-iteration
// prefetch distance (~1000+ cyc, covers HBM); (b) setprio around the MFMA
// cluster; (c) two-stage parallel aux reduction (64 blocks + 1 block).
// Waves = 4 K-quarters; one x->f16 CVT per element; BM=16; grid 1024.

typedef __attribute__((ext_vector_type(8))) _Float16 half8;
typedef __attribute__((ext_vector_type(4))) float f32x4;

constexpr int DD  = 2048;
constexpr int EE  = 64;
constexpr int BM  = 16;          // tokens per block
constexpr int BK  = 128;         // k per staged chunk (each wave: 32-k quarter)
constexpr int NCH = DD / BK;     // 16 chunks
constexpr int NBUF = 4;

#define WVM(N) asm volatile("s_waitcnt vmcnt(" #N ")" ::: "memory")
#define BAR()  asm volatile("s_barrier" ::: "memory")

// ---- pre-kernel (R15-proven): Wg[2048][64] -> fragment-linear wF ----
// wF[(kc*8 + t*2 + p)*512 + l*8 + j] = plane_p( Wg[kc*32+(l>>4)*8+j][t*16+(l&15)] )
__global__ __launch_bounds__(256) void wsplit_kernel(
    const float* __restrict__ Wg, _Float16* __restrict__ wF)
{
    __shared__ float xl[32][65];
    const int tid = threadIdx.x;
    const int kc  = blockIdx.x;          // 64 blocks, 32 k's each
    const int k0  = kc * 32;
#pragma unroll
    for (int r = 0; r < 2; ++r) {
        int slot = tid + r * 256;        // float4 slots 0..511
        int row = slot >> 4, c4 = (slot & 15) << 2;
        *(float4*)&xl[row][c4] = *(const float4*)&Wg[(size_t)(k0 + row) * EE + c4];
    }
    __syncthreads();
    const int t = tid >> 6, l = tid & 63;
    const int e  = t * 16 + (l & 15);
    const int kl = (l >> 4) * 8;
    half8 hh, ll;
#pragma unroll
    for (int j = 0; j < 8; ++j) {
        float v = xl[kl + j][e];
        _Float16 h = (_Float16)v;
        hh[j] = h;
        ll[j] = (_Float16)((v - (float)h) * 4096.f);
    }
    const size_t base = (size_t)(kc * 8 + t * 2) * 512 + (size_t)l * 8;
    *(half8*)&wF[base]       = hh;       // hi plane
    *(half8*)&wF[base + 512] = ll;       // lo plane
}

__global__ __launch_bounds__(256, 4) void gate_kernel(
    const float* __restrict__ x, const _Float16* __restrict__ wF,
    float* __restrict__ gate_out, float* __restrict__ idx_out,
    float* __restrict__ pSum, float* __restrict__ pCnt)
{
    __shared__ __align__(16) union {
        float xs[NBUF][BM][BK];                            // 32 KB staging
        struct { float red[4][BM][68]; float auxsm[2][4][64]; } ep; // 19.5 KB
    } sm;

    const int tid  = threadIdx.x;
    const int kq   = tid >> 6;           // wave = K-quarter of chunk (32 k's)
    const int lane = tid & 63;
    const size_t tok0 = (size_t)blockIdx.x * BM;
    const float* xg = x + tok0 * DD;

    // ---- x staging: 2 dwordx4 DMA per thread per chunk, 32B source-XOR ----
    auto stageX = [&](int buf, int c) {
#pragma unroll
        for (int r = 0; r < 2; ++r) {
            int slot = tid + r * 256;            // float4 slot 0..511
            int row  = slot >> 5;                // 0..15
            int cb   = (slot & 31) << 4;         // dest byte 0..511
            int sb   = cb ^ ((row & 7) << 5);    // source-swizzled byte
            __builtin_amdgcn_global_load_lds(
                xg + (size_t)row * DD + c * BK + (sb >> 2),
                &sm.xs[buf][row][cb >> 2], 16, 0, 0);
        }
    };

    f32x4 aH[4], aL[4];
#pragma unroll
    for (int t = 0; t < 4; ++t) {
        aH[t] = (f32x4){0.f, 0.f, 0.f, 0.f};
        aL[t] = (f32x4){0.f, 0.f, 0.f, 0.f};
    }

    const int rrow = lane & 15;          // token row
    const int rb   = (kq * 128 + ((lane >> 4) * 32)) ^ ((rrow & 7) << 5);

    auto compute = [&](int buf, int c) {
        // w fragments for this wave's 32-k slice (kc = c*4 + kq), all 4 tiles
        const _Float16* wb = wF + (size_t)(c * 4 + kq) * 4096 + (size_t)lane * 8;
        half8 wh[4], wl[4];
#pragma unroll
        for (int t = 0; t < 4; ++t) {
            wh[t] = *(const half8*)(wb + (t * 2) * 512);
            wl[t] = *(const half8*)(wb + (t * 2 + 1) * 512);
        }
        // x fragment: one 8-float read, split once
        const float* p = (const float*)((const char*)&sm.xs[buf][rrow][0] + rb);
        float4 xa = *(const float4*)p;
        float4 xb = *(const float4*)(p + 4);
        half8 ah, al;
        {
            float v;
            v = xa.x; { _Float16 h=(_Float16)v; ah[0]=h; al[0]=(_Float16)((v-(float)h)*4096.f); }
            v = xa.y; { _Float16 h=(_Float16)v; ah[1]=h; al[1]=(_Float16)((v-(float)h)*4096.f); }
            v = xa.z; { _Float16 h=(_Float16)v; ah[2]=h; al[2]=(_Float16)((v-(float)h)*4096.f); }
            v = xa.w; { _Float16 h=(_Float16)v; ah[3]=h; al[3]=(_Float16)((v-(float)h)*4096.f); }
            v = xb.x; { _Float16 h=(_Float16)v; ah[4]=h; al[4]=(_Float16)((v-(float)h)*4096.f); }
            v = xb.y; { _Float16 h=(_Float16)v; ah[5]=h; al[5]=(_Float16)((v-(float)h)*4096.f); }
            v = xb.z; { _Float16 h=(_Float16)v; ah[6]=h; al[6]=(_Float16)((v-(float)h)*4096.f); }
            v = xb.w; { _Float16 h=(_Float16)v; ah[7]=h; al[7]=(_Float16)((v-(float)h)*4096.f); }
        }
        __builtin_amdgcn_s_setprio(1);
#pragma unroll
        for (int t = 0; t < 4; ++t) {
            aH[t] = __builtin_amdgcn_mfma_f32_16x16x32_f16(ah, wh[t], aH[t], 0, 0, 0);
            aL[t] = __builtin_amdgcn_mfma_f32_16x16x32_f16(ah, wl[t], aL[t], 0, 0, 0);
            aL[t] = __builtin_amdgcn_mfma_f32_16x16x32_f16(al, wh[t], aL[t], 0, 0, 0);
        }
        __builtin_amdgcn_s_setprio(0);
    };

    // prologue: 3 stages in flight
    stageX(0, 0);
    stageX(1, 1);
    stageX(2, 2);

#pragma unroll 1
    for (int c = 0; c < NCH; ++c) {
        if (c < NCH - 2)       { WVM(4); }       // stage(c) landed
        else if (c == NCH - 2) { WVM(2); }
        else                   { WVM(0); }
        BAR();                                   // visible to all waves
        if (c + 3 < NCH) stageX((c + 3) & 3, c + 3);  // 3-iter-ahead prefetch
        compute(c & 3, c);
        BAR();                                   // all waves done reading buf
    }

    // ---- K-partials -> LDS (m89-verified C layout), combine planes ----
    __syncthreads();
    const float inv = 1.f / 4096.f;
#pragma unroll
    for (int e = 0; e < 4; ++e) {
        const int row = (lane >> 4) * 4 + e;     // token 0..15
#pragma unroll
        for (int t = 0; t < 4; ++t)
            sm.ep.red[kq][row][t * 16 + (lane & 15)] = aH[t][e] + aL[t][e] * inv;
    }
    __syncthreads();

    // ---- epilogue: wave kq -> tokens [kq*4, kq*4+4); lane = expert ----
    float sumP_acc = 0.f;
    float cnt_acc  = 0.f;
#pragma unroll 1
    for (int tt = 0; tt < 4; ++tt) {
        const int tl = kq * 4 + tt;
        const size_t t = tok0 + tl;
        float v = (sm.ep.red[0][tl][lane] + sm.ep.red[1][tl][lane])
                + (sm.ep.red[2][tl][lane] + sm.ep.red[3][tl][lane]);

        float m = v;
#pragma unroll
        for (int off = 32; off; off >>= 1) m = fmaxf(m, __shfl_xor(m, off, 64));
        float p = expf(v - m);
        float s = p;
#pragma unroll
        for (int off = 32; off; off >>= 1) s += __shfl_xor(s, off, 64);
        float prob = p / s;
        sumP_acc += prob;

        // top-1 (ties -> lowest index, matches lax.top_k)
        float bv = prob; int bi = lane;
#pragma unroll
        for (int off = 32; off; off >>= 1) {
            float ov = __shfl_xor(bv, off, 64);
            int   oi = __shfl_xor(bi, off, 64);
            if (ov > bv || (ov == bv && oi < bi)) { bv = ov; bi = oi; }
        }
        // top-2
        float v2 = (lane == bi) ? -1.f : prob;
        float bv2 = v2; int bi2 = lane;
#pragma unroll
        for (int off = 32; off; off >>= 1) {
            float ov = __shfl_xor(bv2, off, 64);
            int   oi = __shfl_xor(bi2, off, 64);
            if (ov > bv2 || (ov == bv2 && oi < bi2)) { bv2 = ov; bi2 = oi; }
        }

        float denom = bv + bv2;
        float g1 = bv / denom, g2 = bv2 / denom;
        float g = (lane == bi) ? g1 : ((lane == bi2) ? g2 : 0.f);
        gate_out[t * EE + lane] = g;
        if (lane == 0) {
            idx_out[2 * t]     = (float)bi;
            idx_out[2 * t + 1] = (float)bi2;
        }
        cnt_acc += (lane == bi)  ? 1.f : 0.f;
        cnt_acc += (lane == bi2) ? 1.f : 0.f;
    }

    // ---- per-block aux partials (deterministic) ----
    sm.ep.auxsm[0][kq][lane] = sumP_acc;
    sm.ep.auxsm[1][kq][lane] = cnt_acc;
    __syncthreads();
    if (kq == 0) {
        float sp = 0.f, c2 = 0.f;
#pragma unroll
        for (int w = 0; w < 4; ++w) {
            sp += sm.ep.auxsm[0][w][lane];
            c2 += sm.ep.auxsm[1][w][lane];
        }
        pSum[(size_t)blockIdx.x * 64 + lane] = sp;
        pCnt[(size_t)blockIdx.x * 64 + lane] = c2;
    }
}

// ---- aux stage 1: 64 blocks, each reduces 16 source rows (all experts) ----
__global__ __launch_bounds__(256) void aux1_kernel(
    const float* __restrict__ pSum, const float* __restrict__ pCnt,
    float* __restrict__ p2Sum, float* __restrict__ p2Cnt)
{
    const int tid  = threadIdx.x;
    const int wv   = tid >> 6;       // 0..3
    const int lane = tid & 63;       // = expert id
    __shared__ float smem[2][4][64];

    const int r0 = blockIdx.x * 16 + wv * 4;
    float sp = 0.f, cc = 0.f;
#pragma unroll
    for (int u = 0; u < 4; ++u) {
        sp += pSum[(size_t)(r0 + u) * 64 + lane];
        cc += pCnt[(size_t)(r0 + u) * 64 + lane];
    }
    smem[0][wv][lane] = sp;
    smem[1][wv][lane] = cc;
    __syncthreads();
    if (wv == 0) {
        float SP = smem[0][0][lane] + smem[0][1][lane]
                 + smem[0][2][lane] + smem[0][3][lane];
        float CC = smem[1][0][lane] + smem[1][1][lane]
                 + smem[1][2][lane] + smem[1][3][lane];
        p2Sum[(size_t)blockIdx.x * 64 + lane] = SP;
        p2Cnt[(size_t)blockIdx.x * 64 + lane] = CC;
    }
}

// ---- aux stage 2: 1 block over 64 partials ----
__global__ __launch_bounds__(256) void aux2_kernel(
    const float* __restrict__ p2Sum, const float* __restrict__ p2Cnt,
    float* __restrict__ aux_out, float scale)
{
    const int tid  = threadIdx.x;
    const int wv   = tid >> 6;       // 0..3
    const int lane = tid & 63;       // = expert id
    __shared__ float smem[2][4][64];

    float sp = 0.f, cc = 0.f;
#pragma unroll 1
    for (int b = wv * 16; b < wv * 16 + 16; ++b) {
        sp += p2Sum[(size_t)b * 64 + lane];
        cc += p2Cnt[(size_t)b * 64 + lane];
    }
    smem[0][wv][lane] = sp;
    smem[1][wv][lane] = cc;
    __syncthreads();
    if (wv == 0) {
        float SP = smem[0][0][lane] + smem[0][1][lane]
                 + smem[0][2][lane] + smem[0][3][lane];
        float CC = smem[1][0][lane] + smem[1][1][lane]
                 + smem[1][2][lane] + smem[1][3][lane];
        float prod = SP * CC;
#pragma unroll
        for (int off = 32; off; off >>= 1) prod += __shfl_xor(prod, off, 64);
        if (lane == 0) aux_out[0] = prod * scale;
    }
}

extern "C" void kernel_launch(void* const* d_in, const int* in_sizes, int n_in,
                              void* d_out, int out_size, void* d_ws, size_t ws_size,
                              hipStream_t stream) {
    const float* x  = (const float*)d_in[0];
    const float* Wg = (const float*)d_in[1];
    const int T = in_sizes[0] / DD;          // 16384

    float* out      = (float*)d_out;
    float* gate_out = out;                                // T*64
    float* idx_out  = out + (size_t)T * EE;               // T*2 (as float)
    float* aux_out  = idx_out + (size_t)T * 2;            // 1

    const int nblocks = T / BM;                           // 1024
    _Float16* wF = (_Float16*)d_ws;                       // 512 KB frag-linear
    float* pSum  = (float*)(wF + (size_t)64 * 8 * 512);   // 1024*64
    float* pCnt  = pSum + (size_t)nblocks * 64;           // 1024*64
    float* p2Sum = pCnt + (size_t)nblocks * 64;           // 64*64
    float* p2Cnt = p2Sum + 64 * 64;                       // 64*64

    wsplit_kernel<<<64, 256, 0, stream>>>(Wg, wF);
    gate_kernel<<<nblocks, 256, 0, stream>>>(x, wF, gate_out, idx_out, pSum, pCnt);

    const float scale = (float)EE / ((float)T * (float)T);
    aux1_kernel<<<64, 256, 0, stream>>>(pSum, pCnt, p2Sum, p2Cnt);
    aux2_kernel<<<1, 256, 0, stream>>>(p2Sum, p2Cnt, aux_out, scale);
}

// Round 19
// 54.848 us; speedup vs baseline: 1.0746x; 1.0746x over previous
//
#include <hip/hip_runtime.h>

// TopKGate via split-precision f16 MFMA (no fp32 MFMA on CDNA4):
//   x = xh + xl/4096, w = wh + wl/4096 (f16 planes, lo pre-scaled x4096)
//   logits = xh*wh + (xh*wl' + xl'*wh)/4096
// R19 = R17 main loop with ONE barrier per chunk (NBUF=3 makes the second
// redundant: buf (c+2)%3 was read in compute(c-1), which precedes BAR(c) in
// every wave) + R18's two-stage parallel aux. No setprio (hurts lockstep).
// Waves = 4 K-quarters; one x->f16 CVT per element; BM=16; grid 1024.

typedef __attribute__((ext_vector_type(8))) _Float16 half8;
typedef __attribute__((ext_vector_type(4))) float f32x4;

constexpr int DD  = 2048;
constexpr int EE  = 64;
constexpr int BM  = 16;          // tokens per block
constexpr int BK  = 128;         // k per staged chunk (each wave: 32-k quarter)
constexpr int NCH = DD / BK;     // 16 chunks

#define WVM(N) asm volatile("s_waitcnt vmcnt(" #N ")" ::: "memory")
#define BAR()  asm volatile("s_barrier" ::: "memory")

// ---- pre-kernel (R15-proven): Wg[2048][64] -> fragment-linear wF ----
// wF[(kc*8 + t*2 + p)*512 + l*8 + j] = plane_p( Wg[kc*32+(l>>4)*8+j][t*16+(l&15)] )
__global__ __launch_bounds__(256) void wsplit_kernel(
    const float* __restrict__ Wg, _Float16* __restrict__ wF)
{
    __shared__ float xl[32][65];
    const int tid = threadIdx.x;
    const int kc  = blockIdx.x;          // 64 blocks, 32 k's each
    const int k0  = kc * 32;
#pragma unroll
    for (int r = 0; r < 2; ++r) {
        int slot = tid + r * 256;        // float4 slots 0..511
        int row = slot >> 4, c4 = (slot & 15) << 2;
        *(float4*)&xl[row][c4] = *(const float4*)&Wg[(size_t)(k0 + row) * EE + c4];
    }
    __syncthreads();
    const int t = tid >> 6, l = tid & 63;
    const int e  = t * 16 + (l & 15);
    const int kl = (l >> 4) * 8;
    half8 hh, ll;
#pragma unroll
    for (int j = 0; j < 8; ++j) {
        float v = xl[kl + j][e];
        _Float16 h = (_Float16)v;
        hh[j] = h;
        ll[j] = (_Float16)((v - (float)h) * 4096.f);
    }
    const size_t base = (size_t)(kc * 8 + t * 2) * 512 + (size_t)l * 8;
    *(half8*)&wF[base]       = hh;       // hi plane
    *(half8*)&wF[base + 512] = ll;       // lo plane
}

__global__ __launch_bounds__(256, 4) void gate_kernel(
    const float* __restrict__ x, const _Float16* __restrict__ wF,
    float* __restrict__ gate_out, float* __restrict__ idx_out,
    float* __restrict__ pSum, float* __restrict__ pCnt)
{
    __shared__ __align__(16) union {
        float xs[3][BM][BK];                               // 24 KB staging
        struct { float red[4][BM][68]; float auxsm[2][4][64]; } ep; // 19.5 KB
    } sm;

    const int tid  = threadIdx.x;
    const int kq   = tid >> 6;           // wave = K-quarter of chunk (32 k's)
    const int lane = tid & 63;
    const size_t tok0 = (size_t)blockIdx.x * BM;
    const float* xg = x + tok0 * DD;

    // ---- x staging: 2 dwordx4 DMA per thread per chunk, 32B source-XOR ----
    auto stageX = [&](int buf, int c) {
#pragma unroll
        for (int r = 0; r < 2; ++r) {
            int slot = tid + r * 256;            // float4 slot 0..511
            int row  = slot >> 5;                // 0..15
            int cb   = (slot & 31) << 4;         // dest byte 0..511
            int sb   = cb ^ ((row & 7) << 5);    // source-swizzled byte
            __builtin_amdgcn_global_load_lds(
                xg + (size_t)row * DD + c * BK + (sb >> 2),
                &sm.xs[buf][row][cb >> 2], 16, 0, 0);
        }
    };

    f32x4 aH[4], aL[4];
#pragma unroll
    for (int t = 0; t < 4; ++t) {
        aH[t] = (f32x4){0.f, 0.f, 0.f, 0.f};
        aL[t] = (f32x4){0.f, 0.f, 0.f, 0.f};
    }

    const int rrow = lane & 15;          // token row
    const int rb   = (kq * 128 + ((lane >> 4) * 32)) ^ ((rrow & 7) << 5);

    auto compute = [&](int buf, int c) {
        // w fragments for this wave's 32-k slice (kc = c*4 + kq), all 4 tiles
        const _Float16* wb = wF + (size_t)(c * 4 + kq) * 4096 + (size_t)lane * 8;
        half8 wh[4], wl[4];
#pragma unroll
        for (int t = 0; t < 4; ++t) {
            wh[t] = *(const half8*)(wb + (t * 2) * 512);
            wl[t] = *(const half8*)(wb + (t * 2 + 1) * 512);
        }
        // x fragment: one 8-float read, split once
        const float* p = (const float*)((const char*)&sm.xs[buf][rrow][0] + rb);
        float4 xa = *(const float4*)p;
        float4 xb = *(const float4*)(p + 4);
        half8 ah, al;
        {
            float v;
            v = xa.x; { _Float16 h=(_Float16)v; ah[0]=h; al[0]=(_Float16)((v-(float)h)*4096.f); }
            v = xa.y; { _Float16 h=(_Float16)v; ah[1]=h; al[1]=(_Float16)((v-(float)h)*4096.f); }
            v = xa.z; { _Float16 h=(_Float16)v; ah[2]=h; al[2]=(_Float16)((v-(float)h)*4096.f); }
            v = xa.w; { _Float16 h=(_Float16)v; ah[3]=h; al[3]=(_Float16)((v-(float)h)*4096.f); }
            v = xb.x; { _Float16 h=(_Float16)v; ah[4]=h; al[4]=(_Float16)((v-(float)h)*4096.f); }
            v = xb.y; { _Float16 h=(_Float16)v; ah[5]=h; al[5]=(_Float16)((v-(float)h)*4096.f); }
            v = xb.z; { _Float16 h=(_Float16)v; ah[6]=h; al[6]=(_Float16)((v-(float)h)*4096.f); }
            v = xb.w; { _Float16 h=(_Float16)v; ah[7]=h; al[7]=(_Float16)((v-(float)h)*4096.f); }
        }
#pragma unroll
        for (int t = 0; t < 4; ++t) {
            aH[t] = __builtin_amdgcn_mfma_f32_16x16x32_f16(ah, wh[t], aH[t], 0, 0, 0);
            aL[t] = __builtin_amdgcn_mfma_f32_16x16x32_f16(ah, wl[t], aL[t], 0, 0, 0);
            aL[t] = __builtin_amdgcn_mfma_f32_16x16x32_f16(al, wh[t], aL[t], 0, 0, 0);
        }
    };

    // prologue: 2 stages in flight
    stageX(0, 0);
    stageX(1, 1);

    // one barrier per chunk; stage(c+2) safe: buf (c+2)%3 last read in
    // compute(c-1), which precedes every wave's arrival at BAR(c).
#pragma unroll 1
    for (int c = 0; c < NCH; ++c) {
        if (c < NCH - 1) { WVM(2); } else { WVM(0); }  // own stage(c) landed
        BAR();                                   // all waves' stage(c) visible
        compute(c % 3, c);
        if (c + 2 < NCH) stageX((c + 2) % 3, c + 2);
    }

    // ---- K-partials -> LDS (m89-verified C layout), combine planes ----
    __syncthreads();
    const float inv = 1.f / 4096.f;
#pragma unroll
    for (int e = 0; e < 4; ++e) {
        const int row = (lane >> 4) * 4 + e;     // token 0..15
#pragma unroll
        for (int t = 0; t < 4; ++t)
            sm.ep.red[kq][row][t * 16 + (lane & 15)] = aH[t][e] + aL[t][e] * inv;
    }
    __syncthreads();

    // ---- epilogue: wave kq -> tokens [kq*4, kq*4+4); lane = expert ----
    float sumP_acc = 0.f;
    float cnt_acc  = 0.f;
#pragma unroll 1
    for (int tt = 0; tt < 4; ++tt) {
        const int tl = kq * 4 + tt;
        const size_t t = tok0 + tl;
        float v = (sm.ep.red[0][tl][lane] + sm.ep.red[1][tl][lane])
                + (sm.ep.red[2][tl][lane] + sm.ep.red[3][tl][lane]);

        float m = v;
#pragma unroll
        for (int off = 32; off; off >>= 1) m = fmaxf(m, __shfl_xor(m, off, 64));
        float p = expf(v - m);
        float s = p;
#pragma unroll
        for (int off = 32; off; off >>= 1) s += __shfl_xor(s, off, 64);
        float prob = p / s;
        sumP_acc += prob;

        // top-1 (ties -> lowest index, matches lax.top_k)
        float bv = prob; int bi = lane;
#pragma unroll
        for (int off = 32; off; off >>= 1) {
            float ov = __shfl_xor(bv, off, 64);
            int   oi = __shfl_xor(bi, off, 64);
            if (ov > bv || (ov == bv && oi < bi)) { bv = ov; bi = oi; }
        }
        // top-2
        float v2 = (lane == bi) ? -1.f : prob;
        float bv2 = v2; int bi2 = lane;
#pragma unroll
        for (int off = 32; off; off >>= 1) {
            float ov = __shfl_xor(bv2, off, 64);
            int   oi = __shfl_xor(bi2, off, 64);
            if (ov > bv2 || (ov == bv2 && oi < bi2)) { bv2 = ov; bi2 = oi; }
        }

        float denom = bv + bv2;
        float g1 = bv / denom, g2 = bv2 / denom;
        float g = (lane == bi) ? g1 : ((lane == bi2) ? g2 : 0.f);
        gate_out[t * EE + lane] = g;
        if (lane == 0) {
            idx_out[2 * t]     = (float)bi;
            idx_out[2 * t + 1] = (float)bi2;
        }
        cnt_acc += (lane == bi)  ? 1.f : 0.f;
        cnt_acc += (lane == bi2) ? 1.f : 0.f;
    }

    // ---- per-block aux partials (deterministic) ----
    sm.ep.auxsm[0][kq][lane] = sumP_acc;
    sm.ep.auxsm[1][kq][lane] = cnt_acc;
    __syncthreads();
    if (kq == 0) {
        float sp = 0.f, c2 = 0.f;
#pragma unroll
        for (int w = 0; w < 4; ++w) {
            sp += sm.ep.auxsm[0][w][lane];
            c2 += sm.ep.auxsm[1][w][lane];
        }
        pSum[(size_t)blockIdx.x * 64 + lane] = sp;
        pCnt[(size_t)blockIdx.x * 64 + lane] = c2;
    }
}

// ---- aux stage 1: 64 blocks, each reduces 16 source rows (all experts) ----
__global__ __launch_bounds__(256) void aux1_kernel(
    const float* __restrict__ pSum, const float* __restrict__ pCnt,
    float* __restrict__ p2Sum, float* __restrict__ p2Cnt)
{
    const int tid  = threadIdx.x;
    const int wv   = tid >> 6;       // 0..3
    const int lane = tid & 63;       // = expert id
    __shared__ float smem[2][4][64];

    const int r0 = blockIdx.x * 16 + wv * 4;
    float sp = 0.f, cc = 0.f;
#pragma unroll
    for (int u = 0; u < 4; ++u) {
        sp += pSum[(size_t)(r0 + u) * 64 + lane];
        cc += pCnt[(size_t)(r0 + u) * 64 + lane];
    }
    smem[0][wv][lane] = sp;
    smem[1][wv][lane] = cc;
    __syncthreads();
    if (wv == 0) {
        float SP = smem[0][0][lane] + smem[0][1][lane]
                 + smem[0][2][lane] + smem[0][3][lane];
        float CC = smem[1][0][lane] + smem[1][1][lane]
                 + smem[1][2][lane] + smem[1][3][lane];
        p2Sum[(size_t)blockIdx.x * 64 + lane] = SP;
        p2Cnt[(size_t)blockIdx.x * 64 + lane] = CC;
    }
}

// ---- aux stage 2: 1 block over 64 partials ----
__global__ __launch_bounds__(256) void aux2_kernel(
    const float* __restrict__ p2Sum, const float* __restrict__ p2Cnt,
    float* __restrict__ aux_out, float scale)
{
    const int tid  = threadIdx.x;
    const int wv   = tid >> 6;       // 0..3
    const int lane = tid & 63;       // = expert id
    __shared__ float smem[2][4][64];

    float sp = 0.f, cc = 0.f;
#pragma unroll 1
    for (int b = wv * 16; b < wv * 16 + 16; ++b) {
        sp += p2Sum[(size_t)b * 64 + lane];
        cc += p2Cnt[(size_t)b * 64 + lane];
    }
    smem[0][wv][lane] = sp;
    smem[1][wv][lane] = cc;
    __syncthreads();
    if (wv == 0) {
        float SP = smem[0][0][lane] + smem[0][1][lane]
                 + smem[0][2][lane] + smem[0][3][lane];
        float CC = smem[1][0][lane] + smem[1][1][lane]
                 + smem[1][2][lane] + smem[1][3][lane];
        float prod = SP * CC;
#pragma unroll
        for (int off = 32; off; off >>= 1) prod += __shfl_xor(prod, off, 64);
        if (lane == 0) aux_out[0] = prod * scale;
    }
}

extern "C" void kernel_launch(void* const* d_in, const int* in_sizes, int n_in,
                              void* d_out, int out_size, void* d_ws, size_t ws_size,
                              hipStream_t stream) {
    const float* x  = (const float*)d_in[0];
    const float* Wg = (const float*)d_in[1];
    const int T = in_sizes[0] / DD;          // 16384

    float* out      = (float*)d_out;
    float* gate_out = out;                                // T*64
    float* idx_out  = out + (size_t)T * EE;               // T*2 (as float)
    float* aux_out  = idx_out + (size_t)T * 2;            // 1

    const int nblocks = T / BM;                           // 1024
    _Float16* wF = (_Float16*)d_ws;                       // 512 KB frag-linear
    float* pSum  = (float*)(wF + (size_t)64 * 8 * 512);   // 1024*64
    float* pCnt  = pSum + (size_t)nblocks * 64;           // 1024*64
    float* p2Sum = pCnt + (size_t)nblocks * 64;           // 64*64
    float* p2Cnt = p2Sum + 64 * 64;                       // 64*64

    wsplit_kernel<<<64, 256, 0, stream>>>(Wg, wF);
    gate_kernel<<<nblocks, 256, 0, stream>>>(x, wF, gate_out, idx_out, pSum, pCnt);

    const float scale = (float)EE / ((float)T * (float)T);
    aux1_kernel<<<64, 256, 0, stream>>>(pSum, pCnt, p2Sum, p2Cnt);
    aux2_kernel<<<1, 256, 0, stream>>>(p2Sum, p2Cnt, aux_out, scale);
}